// Round 3
// baseline (426.857 us; speedup 1.0000x reference)
//
#include <hip/hip_runtime.h>
#include <hip/hip_bf16.h>

// Problem constants
#define B_   4
#define L_   1024
#define V_   1280
#define NE_  768          // N_EMBD
#define NB_  8            // N_BIN
#define NH_  32           // N_HID
#define NO_  (NB_*NH_)    // 256 = W1 output dim
#define BL_  (B_*L_)      // 4096
#define M2_  (BL_*NB_)    // 32768 = rows of second GEMM
#define NCH_ 64           // i-chunks of 16 for k3

typedef __attribute__((ext_vector_type(8))) short bf16x8;
typedef __attribute__((ext_vector_type(4))) float floatx4;

__device__ __forceinline__ unsigned short f2bf(float f) {
    unsigned int u = __float_as_uint(f);
    u += 0x7FFFu + ((u >> 16) & 1u);      // RNE (inputs are finite, no NaN)
    return (unsigned short)(u >> 16);
}

// ---------------------------------------------------------------------------
// k0: pack h -> bf16 (row-major), W1 -> bf16 TRANSPOSED (256x768),
//     W2 -> bf16 TRANSPOSED (1280x32). Flat work items.
// ---------------------------------------------------------------------------
#define H4_N   (BL_*NE_/4)      // 786432 float4 conversions for h
#define W1T_N  (NO_*NE_)        // 196608
#define W2T_N  (V_*NH_)         // 40960
#define K0_TOT (H4_N + W1T_N + W2T_N)

__global__ __launch_bounds__(256) void k0_pack(const float* __restrict__ h,
                                               const float* __restrict__ W1,
                                               const float* __restrict__ W2,
                                               unsigned short* __restrict__ hb,
                                               unsigned short* __restrict__ W1T,
                                               unsigned short* __restrict__ W2T) {
    int id = blockIdx.x * 256 + threadIdx.x;
    if (id < H4_N) {
        float4 v = ((const float4*)h)[id];
        ushort4 o;
        o.x = f2bf(v.x); o.y = f2bf(v.y); o.z = f2bf(v.z); o.w = f2bf(v.w);
        ((ushort4*)hb)[id] = o;
    } else if (id < H4_N + W1T_N) {
        int j = id - H4_N;          // j = o*768 + k
        int o = j / NE_;
        int k = j - o * NE_;
        W1T[j] = f2bf(W1[(size_t)k * NO_ + o]);
    } else if (id < K0_TOT) {
        int j = id - H4_N - W1T_N;  // j = v*32 + k
        int v = j >> 5;
        int k = j & 31;
        W2T[j] = f2bf(W2[(size_t)k * V_ + v]);
    }
}

// ---------------------------------------------------------------------------
// k1: Xb[4096,256](bf16) = hb[4096,768] @ W1 (via W1T), MFMA 16x16x32 bf16.
// 64x64 tile, 256 threads (4 waves), software-pipelined staging.
// ---------------------------------------------------------------------------
__global__ __launch_bounds__(256) void k1_gemm(const unsigned short* __restrict__ hb,
                                               const unsigned short* __restrict__ W1T,
                                               unsigned short* __restrict__ Xb) {
    __shared__ short A_lds[64][40];   // [row][k] bf16, +8 pad
    __shared__ short Bt_lds[64][40];  // [col][k] bf16, +8 pad

    const int t      = threadIdx.x;
    const int m0     = blockIdx.x * 64;
    const int n0     = blockIdx.y * 64;
    const int l      = t & 63;
    const int w      = t >> 6;
    const int lane15 = l & 15;
    const int quad   = l >> 4;

    const int srow = t >> 2;
    const int sq   = (t & 3) * 8;

    const unsigned short* aptr = hb  + (size_t)(m0 + srow) * NE_ + sq;
    const unsigned short* bptr = W1T + (size_t)(n0 + srow) * NE_ + sq;

    floatx4 acc[4];
#pragma unroll
    for (int i = 0; i < 4; ++i) acc[i] = (floatx4){0.f, 0.f, 0.f, 0.f};

    bf16x8 av = *(const bf16x8*)aptr;
    bf16x8 bv = *(const bf16x8*)bptr;

    for (int k0 = 0; k0 < NE_; k0 += 32) {
        __syncthreads();
        *(bf16x8*)&A_lds[srow][sq]  = av;
        *(bf16x8*)&Bt_lds[srow][sq] = bv;
        __syncthreads();
        if (k0 + 32 < NE_) {
            av = *(const bf16x8*)(aptr + k0 + 32);
            bv = *(const bf16x8*)(bptr + k0 + 32);
        }
        bf16x8 af = *(bf16x8*)&A_lds[w * 16 + lane15][quad * 8];
#pragma unroll
        for (int nt = 0; nt < 4; ++nt) {
            bf16x8 bf = *(bf16x8*)&Bt_lds[nt * 16 + lane15][quad * 8];
            acc[nt] = __builtin_amdgcn_mfma_f32_16x16x32_bf16(af, bf, acc[nt], 0, 0, 0);
        }
    }

    // C/D layout: col = lane&15, row = quad*4 + r
    const int rbase = m0 + w * 16 + quad * 4;
#pragma unroll
    for (int nt = 0; nt < 4; ++nt)
#pragma unroll
        for (int r = 0; r < 4; ++r)
            Xb[(size_t)(rbase + r) * NO_ + n0 + nt * 16 + lane15] = f2bf(acc[nt][r]);
}

// ---------------------------------------------------------------------------
// k2: logits[32768,1280] = Xb[32768,32] @ W2T, one MFMA (K=32) per 16x16
// tile, no LDS. v-split: grid.y=5, 16 v-tiles per block -> 2560 blocks
// (~10/CU) for store-issue parallelism.
// ---------------------------------------------------------------------------
__global__ __launch_bounds__(256) void k2_logits(const unsigned short* __restrict__ Xb,
                                                 const unsigned short* __restrict__ W2T,
                                                 float* __restrict__ outL) {
    const int t      = threadIdx.x;
    const int m0     = blockIdx.x * 64;
    const int nt0    = blockIdx.y * 16;
    const int l      = t & 63;
    const int w      = t >> 6;
    const int lane15 = l & 15;
    const int quad   = l >> 4;

    const int m = m0 + w * 16 + lane15;
    const bf16x8 af = *(const bf16x8*)(Xb + (size_t)m * NH_ + quad * 8);

    const int rbase = m0 + w * 16 + quad * 4;

#pragma unroll 4
    for (int nt = nt0; nt < nt0 + 16; ++nt) {
        bf16x8 bf = *(const bf16x8*)(W2T + (size_t)(nt * 16 + lane15) * NH_ + quad * 8);
        floatx4 c = (floatx4){0.f, 0.f, 0.f, 0.f};
        c = __builtin_amdgcn_mfma_f32_16x16x32_bf16(af, bf, c, 0, 0, 0);
#pragma unroll
        for (int r = 0; r < 4; ++r)
            outL[(size_t)(rbase + r) * V_ + nt * 16 + lane15] = c[r];
    }
}

// ---------------------------------------------------------------------------
// k3a: nxt[b][c][v] = first j >= (c+1)*16 with targets[b,j]==v (L_ if none).
// 20 blocks x 256 threads; serial 1024-step scan, store at chunk boundaries.
// ---------------------------------------------------------------------------
__global__ __launch_bounds__(256) void k3a_nxt(const int* __restrict__ targets,
                                               int* __restrict__ nxt) {
    const int b = blockIdx.x;
    const int v = blockIdx.y * 256 + threadIdx.x;
    __shared__ int tg[L_];
    for (int j = threadIdx.x; j < L_; j += 256) tg[j] = targets[(size_t)b * L_ + j];
    __syncthreads();
    int cur = L_;
    for (int j = L_ - 1; j >= 0; --j) {
        if ((j & 15) == 15)                       // entering chunk c=j>>4
            nxt[((size_t)b * NCH_ + (j >> 4)) * V_ + v] = cur;
        if (tg[j] == v) cur = j;
    }
}

// ---------------------------------------------------------------------------
// k3b: tte + censor mask. Grid (5 vtile, 64 chunk, 4 b) = 1280 single-wave
// blocks. Each lane owns 4 consecutive v -> all stores are float4 (1 KB
// contiguous per store instruction). Scan is only the local 16-wide chunk,
// seeded from nxt.
// ---------------------------------------------------------------------------
__global__ __launch_bounds__(64) void k3b_out(const float* __restrict__ age,
                                              const float* __restrict__ tage,
                                              const int*   __restrict__ targets,
                                              const int*   __restrict__ nxt,
                                              float* __restrict__ outT,
                                              float* __restrict__ outM) {
    __shared__ float ta[L_];
    __shared__ int   tgc[16];
    __shared__ float agc[16];

    const int t  = threadIdx.x;        // 0..63
    const int vt = blockIdx.x;         // 0..4
    const int c  = blockIdx.y;         // 0..63
    const int b  = blockIdx.z;
    const int v0 = vt * 256 + t * 4;

    for (int j = t; j < L_; j += 64) ta[j] = tage[(size_t)b * L_ + j];
    if (t < 16) {
        tgc[t] = targets[(size_t)b * L_ + c * 16 + t];
        agc[t] = age[(size_t)b * L_ + c * 16 + t];
    }
    __syncthreads();

    int4 cur = *(const int4*)&nxt[((size_t)b * NCH_ + c) * V_ + v0];

    for (int ii = 15; ii >= 0; --ii) {
        const int   i  = c * 16 + ii;
        const int   ti = tgc[ii];
        const float ai = agc[ii];

        if (ti == v0 + 0) cur.x = i;
        if (ti == v0 + 1) cur.y = i;
        if (ti == v0 + 2) cur.z = i;
        if (ti == v0 + 3) cur.w = i;

        int ix = cur.x, iy = cur.y, iz = cur.z, iw = cur.w;
        if (v0 == 0 && i >= 1) ix = 0;           // reference's j<i scatter into v=0
        const bool nex = (ix == L_), ney = (iy == L_), nez = (iz == L_), new_ = (iw == L_);

        float4 tt;
        tt.x = ta[nex ? L_ - 1 : ix] - ai;
        tt.y = ta[ney ? L_ - 1 : iy] - ai;
        tt.z = ta[nez ? L_ - 1 : iz] - ai;
        tt.w = ta[new_ ? L_ - 1 : iw] - ai;

        const size_t row = (size_t)(b * L_ + i);
        *(float4*)&outT[row * V_ + v0] = tt;

        const size_t mb = row * NB_ * V_ + v0;
#pragma unroll
        for (int n = 0; n < NB_; ++n) {
            const float lo = n * 1.25f;
            const float hi = (n + 1) * 1.25f;
            float4 m;
            m.x = ((tt.x >= lo && tt.x < hi) || nex)  ? 1.0f : 0.0f;
            m.y = ((tt.y >= lo && tt.y < hi) || ney)  ? 1.0f : 0.0f;
            m.z = ((tt.z >= lo && tt.z < hi) || nez)  ? 1.0f : 0.0f;
            m.w = ((tt.w >= lo && tt.w < hi) || new_) ? 1.0f : 0.0f;
            *(float4*)&outM[mb + (size_t)n * V_] = m;
        }
    }
}

// ---------------------------------------------------------------------------
extern "C" void kernel_launch(void* const* d_in, const int* in_sizes, int n_in,
                              void* d_out, int out_size, void* d_ws, size_t ws_size,
                              hipStream_t stream) {
    const float* h       = (const float*)d_in[0];   // (4,1024,768)
    const float* age     = (const float*)d_in[1];   // (4,1024)
    const float* tage    = (const float*)d_in[2];   // (4,1024)
    /* d_in[3] = delta_t, unused by outputs */
    const int*   targets = (const int*)  d_in[4];   // (4,1024)
    const float* W1      = (const float*)d_in[5];   // (768,256)
    const float* W2      = (const float*)d_in[6];   // (32,1280)

    float* out  = (float*)d_out;
    float* outL = out;                              // 4*1024*8*1280
    float* outT = out + (size_t)BL_ * NB_ * V_;
    float* outM = outT + (size_t)BL_ * V_;

    // workspace layout (all 16B-aligned)
    char* ws = (char*)d_ws;
    unsigned short* hb  = (unsigned short*)(ws);                            // 6,291,456 B
    unsigned short* W1T = (unsigned short*)(ws + 6291456);                  //   393,216 B
    unsigned short* W2T = (unsigned short*)(ws + 6291456 + 393216);         //    81,920 B
    unsigned short* Xb  = (unsigned short*)(ws + 6291456 + 393216 + 81920); // 2,097,152 B
    int*            nxt = (int*)(ws + 6291456 + 393216 + 81920 + 2097152);  // 1,310,720 B

    k0_pack  <<<(K0_TOT + 255) / 256, 256, 0, stream>>>(h, W1, W2, hb, W1T, W2T);
    k3a_nxt  <<<dim3(B_, V_/256), 256, 0, stream>>>(targets, nxt);
    k1_gemm  <<<dim3(BL_/64, NO_/64), 256, 0, stream>>>(hb, W1T, Xb);
    k2_logits<<<dim3(M2_/64, 5), 256, 0, stream>>>(Xb, W2T, outL);
    k3b_out  <<<dim3(5, NCH_, B_), 64, 0, stream>>>(age, tage, targets, nxt, outT, outM);
}